// Round 1
// baseline (504.792 us; speedup 1.0000x reference)
//
#include <hip/hip_runtime.h>
#include <hip/hip_bf16.h>

typedef __bf16 bf16;
typedef __attribute__((ext_vector_type(8))) __bf16 bf16x8;
typedef __attribute__((ext_vector_type(4))) __bf16 bf16x4;
typedef __attribute__((ext_vector_type(4))) float f32x4;

#define NTOK 98
#define NP   112          // padded tokens (7*16)
#define DIM  128
#define NH   4
#define HD   32
#define SCALE_Q 0.17677669529663687f   // 32^-0.5

// LDS strides (bf16 elements) — chosen for 16B-aligned ds_read_b128 and <=2-way bank aliasing
#define SXP 136
#define SKP 40
#define SVP 136
#define SPP 136
#define SQP 40

// ws byte offsets
#define WS_WTQ  0                       // bf16 [384][128]  = 98304 B
#define WS_PT   98304                   // bf16 [128][128]  = 32768 B
#define WS_BIAS 131072                  // f32  [4][98][98] = 153664 B

__global__ __launch_bounds__(256) void prep_kernel(
    const float* __restrict__ qkv_w, const float* __restrict__ proj_w,
    const float* __restrict__ table, const int* __restrict__ rel_index,
    bf16* __restrict__ WTq, bf16* __restrict__ PT, float* __restrict__ biasf)
{
  int i = blockIdx.x * 256 + threadIdx.x;
  if (i < 384*128) {
    int n = i >> 7, k = i & 127;
    WTq[i] = (bf16)qkv_w[k*384 + n];
  } else if (i < 384*128 + 128*128) {
    int j = i - 384*128; int n = j >> 7, k = j & 127;
    PT[j] = (bf16)proj_w[k*128 + n];
  } else if (i < 384*128 + 128*128 + 98*98) {
    int j = i - (384*128 + 128*128);
    int idx = rel_index[j];
#pragma unroll
    for (int h = 0; h < 4; ++h) biasf[h*9604 + j] = table[idx*4 + h];
  }
}

__global__ __launch_bounds__(512, 2) void win_attn_kernel(
    const float* __restrict__ x, const float* __restrict__ mask,
    const float* __restrict__ qkv_b, const float* __restrict__ proj_b,
    const bf16* __restrict__ WTq, const bf16* __restrict__ PT,
    const float* __restrict__ biasf, float* __restrict__ out)
{
  __shared__ bf16 sX[NP*SXP];        // x (bf16) during GEMM phases; reused as O afterwards
  __shared__ bf16 sK[NH*NP*SKP];     // K  [h][tok][d]
  __shared__ bf16 sVT[NH*HD*SVP];    // V^T [h][d][tok(128 padded)]
  __shared__ bf16 sQs[8*16*SQP];     // per-wave Q-tile scratch
  __shared__ bf16 sPs[8*16*SPP];     // per-wave P-tile scratch

  const int b = blockIdx.x;
  const int w = b & 63;
  const int tid = threadIdx.x;
  const int wave = tid >> 6, lane = tid & 63;
  const int quad = lane >> 4, l16 = lane & 15;
  const f32x4 fzero = {0.f, 0.f, 0.f, 0.f};

  // ---------- phase 1: stage x -> bf16 LDS, zero pads ----------
  {
    const float* xb = x + (size_t)b * (NTOK*DIM);
    for (int i = tid; i < NTOK*32; i += 512) {
      int row = i >> 5, c4 = (i & 31) << 2;
      const float4 v = *(const float4*)(xb + row*DIM + c4);
      bf16x4 pk; pk[0]=(bf16)v.x; pk[1]=(bf16)v.y; pk[2]=(bf16)v.z; pk[3]=(bf16)v.w;
      *(bf16x4*)&sX[row*SXP + c4] = pk;
    }
    for (int i = tid; i < 14*32; i += 512) {      // pad rows 98..111 = 0
      int row = NTOK + (i >> 5), c4 = (i & 31) << 2;
      uint2 z; z.x = 0; z.y = 0;
      *(uint2*)&sX[row*SXP + c4] = z;
    }
    {                                              // VT pad cols 112..127 = 0 (avoid 0*NaN in PV)
      int h = tid >> 7, rem = tid & 127, d = rem >> 2, c0 = 112 + ((rem & 3) << 2);
      uint2 z; z.x = 0; z.y = 0;
      *(uint2*)&sVT[(h*HD + d)*SVP + c0] = z;
    }
  }
  __syncthreads();

  // ---------- phase 2: K and V (16 jobs = 4 heads x {K0,K1,V0,V1}) ----------
#pragma unroll
  for (int j = 0; j < 2; ++j) {
    const int job = wave*2 + j;
    const int h = job >> 2, part = job & 3;
    const bool isK = part < 2;
    const int ncol = (isK ? DIM + h*HD + part*16 : 2*DIM + h*HD + (part-2)*16) + l16;
    bf16x8 bfr[4];
#pragma unroll
    for (int ks = 0; ks < 4; ++ks)
      bfr[ks] = *(const bf16x8*)(WTq + ncol*DIM + ks*32 + quad*8);
    const float cb = qkv_b[ncol];
#pragma unroll
    for (int mt = 0; mt < 7; ++mt) {
      f32x4 acc = fzero;
#pragma unroll
      for (int ks = 0; ks < 4; ++ks) {
        const bf16x8 a = *(const bf16x8*)&sX[(mt*16 + l16)*SXP + ks*32 + quad*8];
        acc = __builtin_amdgcn_mfma_f32_16x16x32_bf16(a, bfr[ks], acc, 0, 0, 0);
      }
      const int tb = mt*16 + quad*4;
      if (isK) {
        const int d = part*16 + l16;
#pragma unroll
        for (int r = 0; r < 4; ++r)
          sK[(h*NP + tb + r)*SKP + d] = (bf16)(acc[r] + cb);
      } else {
        const int d = (part-2)*16 + l16;
        bf16x4 pk;
#pragma unroll
        for (int r = 0; r < 4; ++r) pk[r] = (bf16)(acc[r] + cb);
        *(bf16x4*)&sVT[(h*HD + d)*SVP + tb] = pk;
      }
    }
  }
  __syncthreads();

  // ---------- phase 3: per wave-pair = head; Q on the fly, S, softmax, PV ----------
  {
    const int h = wave >> 1, sub = wave & 1;
    bf16x8 qb[2][4];
#pragma unroll
    for (int nt2 = 0; nt2 < 2; ++nt2)
#pragma unroll
      for (int ks = 0; ks < 4; ++ks)
        qb[nt2][ks] = *(const bf16x8*)(WTq + (h*HD + nt2*16 + l16)*DIM + ks*32 + quad*8);
    const float qbias0 = qkv_b[h*HD + l16];
    const float qbias1 = qkv_b[h*HD + 16 + l16];
    bf16* sQ = sQs + wave*16*SQP;
    bf16* sP = sPs + wave*16*SPP;
    {   // zero P pad cols 112..127 once (stay zero)
      int row = lane >> 2, c0 = 112 + ((lane & 3) << 2);
      uint2 z; z.x = 0; z.y = 0;
      *(uint2*)&sP[row*SPP + c0] = z;
    }
    const float* bias_h = biasf + h*9604;
    const float* mask_w = mask + w*9604;

    f32x4 oacc0 = fzero, oacc1 = fzero;
#pragma unroll 1
    for (int it = 0; it < 4; ++it) {
      const int mt = sub + it*2;
      const bool valid = mt < 7;
      if (valid) {
        // Q-tile [16 x 32] on the fly
        f32x4 qa0 = fzero, qa1 = fzero;
#pragma unroll
        for (int ks = 0; ks < 4; ++ks) {
          const bf16x8 a = *(const bf16x8*)&sX[(mt*16 + l16)*SXP + ks*32 + quad*8];
          qa0 = __builtin_amdgcn_mfma_f32_16x16x32_bf16(a, qb[0][ks], qa0, 0, 0, 0);
          qa1 = __builtin_amdgcn_mfma_f32_16x16x32_bf16(a, qb[1][ks], qa1, 0, 0, 0);
        }
#pragma unroll
        for (int r = 0; r < 4; ++r) {
          sQ[(quad*4 + r)*SQP + l16]      = (bf16)((qa0[r] + qbias0) * SCALE_Q);
          sQ[(quad*4 + r)*SQP + 16 + l16] = (bf16)((qa1[r] + qbias1) * SCALE_Q);
        }
        const bf16x8 aq = *(const bf16x8*)&sQ[l16*SQP + quad*8];
        // S = Q K^T : 7 col-tiles
        f32x4 s[7];
#pragma unroll
        for (int nt = 0; nt < 7; ++nt) {
          const bf16x8 bk = *(const bf16x8*)&sK[(h*NP + nt*16 + l16)*SKP + quad*8];
          s[nt] = __builtin_amdgcn_mfma_f32_16x16x32_bf16(aq, bk, fzero, 0, 0, 0);
        }
        // bias + mask + row softmax (rows live in 16-lane groups)
#pragma unroll
        for (int r = 0; r < 4; ++r) {
          const int row = mt*16 + quad*4 + r;
          const bool rowok = row < NTOK;
          float mx = -3.0e38f;
#pragma unroll
          for (int nt = 0; nt < 7; ++nt) {
            const int col = nt*16 + l16;
            float sv;
            if (rowok && col < NTOK)
              sv = s[nt][r] + bias_h[row*NTOK + col] + mask_w[row*NTOK + col];
            else
              sv = -1.0e30f;
            s[nt][r] = sv;
            mx = fmaxf(mx, sv);
          }
#pragma unroll
          for (int off = 1; off < 16; off <<= 1)
            mx = fmaxf(mx, __shfl_xor(mx, off, 64));
          float sum = 0.f;
#pragma unroll
          for (int nt = 0; nt < 7; ++nt) {
            const float p = __expf(s[nt][r] - mx);
            s[nt][r] = p;
            sum += p;
          }
#pragma unroll
          for (int off = 1; off < 16; off <<= 1)
            sum += __shfl_xor(sum, off, 64);
          const float inv = __builtin_amdgcn_rcpf(sum);
#pragma unroll
          for (int nt = 0; nt < 7; ++nt)
            sP[(quad*4 + r)*SPP + nt*16 + l16] = (bf16)(s[nt][r] * inv);
        }
        // O-tile = P V  (K = 128, padded region contributes 0)
        oacc0 = fzero; oacc1 = fzero;
#pragma unroll
        for (int ks = 0; ks < 4; ++ks) {
          const bf16x8 ap = *(const bf16x8*)&sP[l16*SPP + ks*32 + quad*8];
          const bf16x8 bv0 = *(const bf16x8*)&sVT[(h*HD + l16)*SVP + ks*32 + quad*8];
          const bf16x8 bv1 = *(const bf16x8*)&sVT[(h*HD + 16 + l16)*SVP + ks*32 + quad*8];
          oacc0 = __builtin_amdgcn_mfma_f32_16x16x32_bf16(ap, bv0, oacc0, 0, 0, 0);
          oacc1 = __builtin_amdgcn_mfma_f32_16x16x32_bf16(ap, bv1, oacc1, 0, 0, 0);
        }
      }
      // all waves finished READING sX rows for this iteration before anyone overwrites them with O
      __syncthreads();
      if (valid) {
#pragma unroll
        for (int r = 0; r < 4; ++r) {
          sX[(mt*16 + quad*4 + r)*SXP + h*HD + l16]      = (bf16)(oacc0[r]);
          sX[(mt*16 + quad*4 + r)*SXP + h*HD + 16 + l16] = (bf16)(oacc1[r]);
        }
      }
    }
  }
  __syncthreads();

  // ---------- phase 4: proj GEMM + store ----------
  {
    const int nt = wave;   // output col-tile 0..7
    bf16x8 pbf[4];
#pragma unroll
    for (int ks = 0; ks < 4; ++ks)
      pbf[ks] = *(const bf16x8*)(PT + (nt*16 + l16)*DIM + ks*32 + quad*8);
    const float pb = proj_b[nt*16 + l16];
    float* outb = out + (size_t)b * (NTOK*DIM);
#pragma unroll
    for (int mt = 0; mt < 7; ++mt) {
      f32x4 acc = fzero;
#pragma unroll
      for (int ks = 0; ks < 4; ++ks) {
        const bf16x8 a = *(const bf16x8*)&sX[(mt*16 + l16)*SXP + ks*32 + quad*8];
        acc = __builtin_amdgcn_mfma_f32_16x16x32_bf16(a, pbf[ks], acc, 0, 0, 0);
      }
#pragma unroll
      for (int r = 0; r < 4; ++r) {
        const int row = mt*16 + quad*4 + r;
        if (row < NTOK)
          outb[row*DIM + nt*16 + l16] = acc[r] + pb;
      }
    }
  }
}

extern "C" void kernel_launch(void* const* d_in, const int* in_sizes, int n_in,
                              void* d_out, int out_size, void* d_ws, size_t ws_size,
                              hipStream_t stream)
{
  const float* x      = (const float*)d_in[0];
  const float* mask   = (const float*)d_in[1];
  const float* qkv_w  = (const float*)d_in[2];
  const float* qkv_b  = (const float*)d_in[3];
  const float* table  = (const float*)d_in[4];
  const int*   rel    = (const int*)d_in[5];
  const float* proj_w = (const float*)d_in[6];
  const float* proj_b = (const float*)d_in[7];
  float* out = (float*)d_out;
  char* ws = (char*)d_ws;
  bf16*  WTq   = (bf16*)(ws + WS_WTQ);
  bf16*  PT    = (bf16*)(ws + WS_PT);
  float* biasf = (float*)(ws + WS_BIAS);

  const int prep_total = 384*128 + 128*128 + 98*98;
  prep_kernel<<<(prep_total + 255)/256, 256, 0, stream>>>(qkv_w, proj_w, table, rel, WTq, PT, biasf);
  win_attn_kernel<<<2048, 512, 0, stream>>>(x, mask, qkv_b, proj_b, WTq, PT, biasf, out);
}

// Round 3
// 383.029 us; speedup vs baseline: 1.3179x; 1.3179x over previous
//
#include <hip/hip_runtime.h>
#include <hip/hip_bf16.h>

typedef __bf16 bf16;
typedef __attribute__((ext_vector_type(8))) __bf16 bf16x8;
typedef __attribute__((ext_vector_type(4))) __bf16 bf16x4;
typedef __attribute__((ext_vector_type(4))) float f32x4;

#define NTOK 98
#define NP   112
#define DIM  128
#define NH   4
#define HD   32
#define SCALE_Q 0.17677669529663687f

#define SXP 136
#define SKP 40
#define SVP 136
#define SPP 136
#define SQP 40

// ---- fast-path ws layout (bytes) ----
#define WS_WTQ  0ULL                    // bf16 [384][128]            98304
#define WS_PT   98304ULL                // bf16 [128][128]            32768
#define WS_BM   131072ULL               // f32  [64][4][98][112]   11239424
#define WS_QS   11370496ULL             // bf16 [2048*4][112][32]  58720256
#define WS_KS   70090752ULL             // bf16 [2048*4][112][32]  58720256
#define WS_VTS  128811008ULL            // bf16 [2048*4][32][128]  67108864
#define WS_NEED 195919872ULL

// ===================== fast path =====================

__global__ __launch_bounds__(256) void prep2_kernel(
    const float* __restrict__ qkv_w, const float* __restrict__ proj_w,
    bf16* __restrict__ WTq, bf16* __restrict__ PT)
{
  int i = blockIdx.x * 256 + threadIdx.x;
  if (i < 384*128) {
    int n = i >> 7, k = i & 127;
    WTq[i] = (bf16)qkv_w[k*384 + n];
  } else if (i < 384*128 + 128*128) {
    int j = i - 384*128; int n = j >> 7, k = j & 127;
    PT[j] = (bf16)proj_w[k*128 + n];
  }
}

// bm2[w][h][col][row(112 pad)] = table[rel[row*98+col]][h] + mask[w][row][col]
__global__ __launch_bounds__(256) void bm_kernel(
    const float* __restrict__ table, const int* __restrict__ rel,
    const float* __restrict__ mask, float* __restrict__ bm2)
{
  int g = blockIdx.x * 256 + threadIdx.x;
  if (g >= 64*4*98*112) return;
  int row = g % 112;
  int rest = g / 112;
  int col = rest % 98;
  int rest2 = rest / 98;
  int h = rest2 & 3;
  int w = rest2 >> 2;
  float v = 0.f;
  if (row < 98) {
    int ij = row*98 + col;
    v = table[rel[ij]*4 + h] + mask[w*9604 + ij];
  }
  bm2[g] = v;
}

__global__ __launch_bounds__(512, 4) void qkv_kernel(
    const float* __restrict__ x, const float* __restrict__ qkv_b,
    const bf16* __restrict__ WTq,
    bf16* __restrict__ Qs, bf16* __restrict__ Ks, bf16* __restrict__ VTs)
{
  __shared__ bf16 sX[NP*SXP];
  __shared__ bf16 sVT[128*SVP];      // [h*32+d][tok]
  const int b = blockIdx.x;
  const int tid = threadIdx.x;
  const int wave = tid >> 6, lane = tid & 63;
  const int quad = lane >> 4, l16 = lane & 15;
  const f32x4 fzero = {0.f, 0.f, 0.f, 0.f};

  const float* xb = x + (size_t)b * (NTOK*DIM);
  for (int i = tid; i < NTOK*32; i += 512) {
    int row = i >> 5, c4 = (i & 31) << 2;
    const float4 v = *(const float4*)(xb + row*DIM + c4);
    bf16x4 pk; pk[0]=(bf16)v.x; pk[1]=(bf16)v.y; pk[2]=(bf16)v.z; pk[3]=(bf16)v.w;
    *(bf16x4*)&sX[row*SXP + c4] = pk;
  }
  for (int i = tid; i < 14*32; i += 512) {
    int row = NTOK + (i >> 5), c4 = (i & 31) << 2;
    uint2 z; z.x = 0; z.y = 0;
    *(uint2*)&sX[row*SXP + c4] = z;
  }
  for (int i = tid; i < 128*2; i += 512) {   // sVT pad cols 112..127 = 0 (FULL 16 cols: uint4 = 8 bf16)
    int row = i >> 1, c0 = 112 + (i & 1) * 8;
    uint4 z; z.x = 0; z.y = 0; z.z = 0; z.w = 0;
    *(uint4*)&sVT[row*SVP + c0] = z;
  }
  __syncthreads();

  const size_t bh4 = (size_t)b * 4;
#pragma unroll
  for (int jj = 0; jj < 3; ++jj) {
    const int job = wave + jj*8;
    const int t = job >> 3, h = (job & 7) >> 1, half = job & 1;
    const int ncol = t*128 + h*HD + half*16 + l16;
    bf16x8 wf[4];
#pragma unroll
    for (int ks = 0; ks < 4; ++ks)
      wf[ks] = *(const bf16x8*)(WTq + ncol*DIM + ks*32 + quad*8);
    const float cb = qkv_b[ncol];
#pragma unroll
    for (int mt = 0; mt < 7; ++mt) {
      f32x4 acc = fzero;
#pragma unroll
      for (int ks = 0; ks < 4; ++ks) {
        const bf16x8 a = *(const bf16x8*)&sX[(mt*16 + l16)*SXP + ks*32 + quad*8];
        acc = __builtin_amdgcn_mfma_f32_16x16x32_bf16(a, wf[ks], acc, 0, 0, 0);
      }
      if (t == 0) {
        bf16* qp = Qs + (bh4 + h)*(NP*HD) + half*16 + l16;
#pragma unroll
        for (int r = 0; r < 4; ++r) {
          int row = mt*16 + quad*4 + r;
          qp[row*HD] = (row < NTOK) ? (bf16)((acc[r] + cb) * SCALE_Q) : (bf16)0.f;
        }
      } else if (t == 1) {
        bf16* kp = Ks + (bh4 + h)*(NP*HD) + half*16 + l16;
#pragma unroll
        for (int r = 0; r < 4; ++r) {
          int row = mt*16 + quad*4 + r;
          kp[row*HD] = (row < NTOK) ? (bf16)(acc[r] + cb) : (bf16)0.f;
        }
      } else {
        const int tb = mt*16 + quad*4;
        bf16x4 pk;
#pragma unroll
        for (int r = 0; r < 4; ++r)
          pk[r] = (tb + r < NTOK) ? (bf16)(acc[r] + cb) : (bf16)0.f;
        *(bf16x4*)&sVT[(h*HD + half*16 + l16)*SVP + tb] = pk;
      }
    }
  }
  __syncthreads();

  bf16* vt = VTs + bh4*(HD*128);
#pragma unroll
  for (int i = tid; i < 128*16; i += 512) {
    int row = i >> 4, seg = i & 15;
    *(bf16x8*)(vt + row*128 + seg*8) = *(const bf16x8*)&sVT[row*SVP + seg*8];
  }
}

__global__ __launch_bounds__(256, 3) void attn_kernel(
    const float* __restrict__ proj_b,
    const bf16* __restrict__ Qs, const bf16* __restrict__ Ks,
    const bf16* __restrict__ VTs, const bf16* __restrict__ PT,
    const float* __restrict__ bm2, float* __restrict__ out)
{
  __shared__ bf16 sO[NP*SXP];
  __shared__ bf16 sPs[4*16*SPP];
  const int b = blockIdx.x, w = b & 63;
  const int tid = threadIdx.x;
  const int wave = tid >> 6, lane = tid & 63;
  const int quad = lane >> 4, l16 = lane & 15;
  const int h = wave;
  const f32x4 fzero = {0.f, 0.f, 0.f, 0.f};
  const f32x4 fneg = {-1.0e30f, -1.0e30f, -1.0e30f, -1.0e30f};

  const size_t bh = (size_t)b*4 + h;
  const bf16* Qh = Qs + bh*(NP*HD);
  const bf16* Kh = Ks + bh*(NP*HD);
  const bf16* Vh = VTs + bh*(HD*128);
  bf16* sP = sPs + wave*16*SPP;
  {   // zero P pad cols 112..127 (written once, never touched again)
    int row = lane >> 2, c0 = 112 + ((lane & 3) << 2);
    uint2 z; z.x = 0; z.y = 0;
    *(uint2*)&sP[row*SPP + c0] = z;
  }

  // persistent fragments: K (7) and V^T (2x4), reused across all 7 q-tiles
  bf16x8 bk[7];
#pragma unroll
  for (int nt = 0; nt < 7; ++nt)
    bk[nt] = *(const bf16x8*)(Kh + (nt*16 + l16)*HD + quad*8);
  bf16x8 bv[2][4];
#pragma unroll
  for (int dt = 0; dt < 2; ++dt)
#pragma unroll
    for (int ks = 0; ks < 4; ++ks)
      bv[dt][ks] = *(const bf16x8*)(Vh + (dt*16 + l16)*128 + ks*32 + quad*8);

  const float* bmh = bm2 + ((size_t)(w*4 + h))*(98*NP);

  bf16x8 aq = *(const bf16x8*)(Qh + l16*HD + quad*8);
#pragma unroll 1
  for (int mt = 0; mt < 7; ++mt) {
    const bf16x8 aqn = (mt < 6) ? *(const bf16x8*)(Qh + ((mt+1)*16 + l16)*HD + quad*8) : aq;
    f32x4 s[7];
#pragma unroll
    for (int nt = 0; nt < 7; ++nt)
      s[nt] = __builtin_amdgcn_mfma_f32_16x16x32_bf16(aq, bk[nt], fzero, 0, 0, 0);
    // add bias+mask (vectorized over the 4 accum rows)
#pragma unroll
    for (int nt = 0; nt < 7; ++nt) {
      const int col = nt*16 + l16;
      if (col < NTOK) {
        const f32x4 bmv = *(const f32x4*)(bmh + col*NP + mt*16 + quad*4);
        s[nt] = s[nt] + bmv;
      } else {
        s[nt] = fneg;
      }
    }
    // row softmax (rows live in 16-lane groups)
#pragma unroll
    for (int r = 0; r < 4; ++r) {
      const int row = mt*16 + quad*4 + r;
      const bool rowok = row < NTOK;
      float sv[7];
      float mx = -3.0e38f;
#pragma unroll
      for (int nt = 0; nt < 7; ++nt) {
        float v = rowok ? s[nt][r] : -1.0e30f;
        sv[nt] = v;
        mx = fmaxf(mx, v);
      }
#pragma unroll
      for (int off = 1; off < 16; off <<= 1)
        mx = fmaxf(mx, __shfl_xor(mx, off, 64));
      float sum = 0.f;
#pragma unroll
      for (int nt = 0; nt < 7; ++nt) {
        const float p = __expf(sv[nt] - mx);
        sv[nt] = p;
        sum += p;
      }
#pragma unroll
      for (int off = 1; off < 16; off <<= 1)
        sum += __shfl_xor(sum, off, 64);
      const float inv = __builtin_amdgcn_rcpf(sum);
#pragma unroll
      for (int nt = 0; nt < 7; ++nt)
        sP[(quad*4 + r)*SPP + nt*16 + l16] = (bf16)(sv[nt] * inv);
    }
    // O-tile = P V
    f32x4 o0 = fzero, o1 = fzero;
#pragma unroll
    for (int ks = 0; ks < 4; ++ks) {
      const bf16x8 ap = *(const bf16x8*)&sP[l16*SPP + ks*32 + quad*8];
      o0 = __builtin_amdgcn_mfma_f32_16x16x32_bf16(ap, bv[0][ks], o0, 0, 0, 0);
      o1 = __builtin_amdgcn_mfma_f32_16x16x32_bf16(ap, bv[1][ks], o1, 0, 0, 0);
    }
#pragma unroll
    for (int r = 0; r < 4; ++r) {
      sO[(mt*16 + quad*4 + r)*SXP + h*HD + l16]      = (bf16)o0[r];
      sO[(mt*16 + quad*4 + r)*SXP + h*HD + 16 + l16] = (bf16)o1[r];
    }
    aq = aqn;
  }
  __syncthreads();

  // proj GEMM from sO; each wave does col-tiles {wave, wave+4}
  float* outb = out + (size_t)b * (NTOK*DIM);
#pragma unroll
  for (int nn = 0; nn < 2; ++nn) {
    const int nt2 = wave + nn*4;
    bf16x8 pf[4];
#pragma unroll
    for (int ks = 0; ks < 4; ++ks)
      pf[ks] = *(const bf16x8*)(PT + (nt2*16 + l16)*DIM + ks*32 + quad*8);
    const float pb = proj_b[nt2*16 + l16];
#pragma unroll
    for (int mt = 0; mt < 7; ++mt) {
      f32x4 acc = fzero;
#pragma unroll
      for (int ks = 0; ks < 4; ++ks) {
        const bf16x8 a = *(const bf16x8*)&sO[(mt*16 + l16)*SXP + ks*32 + quad*8];
        acc = __builtin_amdgcn_mfma_f32_16x16x32_bf16(a, pf[ks], acc, 0, 0, 0);
      }
#pragma unroll
      for (int r = 0; r < 4; ++r) {
        const int row = mt*16 + quad*4 + r;
        if (row < NTOK)
          outb[row*DIM + nt2*16 + l16] = acc[r] + pb;
      }
    }
  }
}

// ===================== fallback path (round-1 kernels, used if ws too small) =====================

__global__ __launch_bounds__(256) void prep_kernel(
    const float* __restrict__ qkv_w, const float* __restrict__ proj_w,
    const float* __restrict__ table, const int* __restrict__ rel_index,
    bf16* __restrict__ WTq, bf16* __restrict__ PT, float* __restrict__ biasf)
{
  int i = blockIdx.x * 256 + threadIdx.x;
  if (i < 384*128) {
    int n = i >> 7, k = i & 127;
    WTq[i] = (bf16)qkv_w[k*384 + n];
  } else if (i < 384*128 + 128*128) {
    int j = i - 384*128; int n = j >> 7, k = j & 127;
    PT[j] = (bf16)proj_w[k*128 + n];
  } else if (i < 384*128 + 128*128 + 98*98) {
    int j = i - (384*128 + 128*128);
    int idx = rel_index[j];
#pragma unroll
    for (int h = 0; h < 4; ++h) biasf[h*9604 + j] = table[idx*4 + h];
  }
}

__global__ __launch_bounds__(512, 2) void win_attn_kernel(
    const float* __restrict__ x, const float* __restrict__ mask,
    const float* __restrict__ qkv_b, const float* __restrict__ proj_b,
    const bf16* __restrict__ WTq, const bf16* __restrict__ PT,
    const float* __restrict__ biasf, float* __restrict__ out)
{
  __shared__ bf16 sX[NP*SXP];
  __shared__ bf16 sK[NH*NP*SKP];
  __shared__ bf16 sVT[NH*HD*SVP];
  __shared__ bf16 sQs[8*16*SQP];
  __shared__ bf16 sPs[8*16*SPP];

  const int b = blockIdx.x;
  const int w = b & 63;
  const int tid = threadIdx.x;
  const int wave = tid >> 6, lane = tid & 63;
  const int quad = lane >> 4, l16 = lane & 15;
  const f32x4 fzero = {0.f, 0.f, 0.f, 0.f};

  {
    const float* xb = x + (size_t)b * (NTOK*DIM);
    for (int i = tid; i < NTOK*32; i += 512) {
      int row = i >> 5, c4 = (i & 31) << 2;
      const float4 v = *(const float4*)(xb + row*DIM + c4);
      bf16x4 pk; pk[0]=(bf16)v.x; pk[1]=(bf16)v.y; pk[2]=(bf16)v.z; pk[3]=(bf16)v.w;
      *(bf16x4*)&sX[row*SXP + c4] = pk;
    }
    for (int i = tid; i < 14*32; i += 512) {
      int row = NTOK + (i >> 5), c4 = (i & 31) << 2;
      uint2 z; z.x = 0; z.y = 0;
      *(uint2*)&sX[row*SXP + c4] = z;
    }
    {
      int h = tid >> 7, rem = tid & 127, d = rem >> 2, c0 = 112 + ((rem & 3) << 2);
      uint2 z; z.x = 0; z.y = 0;
      *(uint2*)&sVT[(h*HD + d)*SVP + c0] = z;
    }
  }
  __syncthreads();

#pragma unroll
  for (int j = 0; j < 2; ++j) {
    const int job = wave*2 + j;
    const int h = job >> 2, part = job & 3;
    const bool isK = part < 2;
    const int ncol = (isK ? DIM + h*HD + part*16 : 2*DIM + h*HD + (part-2)*16) + l16;
    bf16x8 bfr[4];
#pragma unroll
    for (int ks = 0; ks < 4; ++ks)
      bfr[ks] = *(const bf16x8*)(WTq + ncol*DIM + ks*32 + quad*8);
    const float cb = qkv_b[ncol];
#pragma unroll
    for (int mt = 0; mt < 7; ++mt) {
      f32x4 acc = fzero;
#pragma unroll
      for (int ks = 0; ks < 4; ++ks) {
        const bf16x8 a = *(const bf16x8*)&sX[(mt*16 + l16)*SXP + ks*32 + quad*8];
        acc = __builtin_amdgcn_mfma_f32_16x16x32_bf16(a, bfr[ks], acc, 0, 0, 0);
      }
      const int tb = mt*16 + quad*4;
      if (isK) {
        const int d = part*16 + l16;
#pragma unroll
        for (int r = 0; r < 4; ++r)
          sK[(h*NP + tb + r)*SKP + d] = (bf16)(acc[r] + cb);
      } else {
        const int d = (part-2)*16 + l16;
        bf16x4 pk;
#pragma unroll
        for (int r = 0; r < 4; ++r) pk[r] = (bf16)(acc[r] + cb);
        *(bf16x4*)&sVT[(h*HD + d)*SVP + tb] = pk;
      }
    }
  }
  __syncthreads();

  {
    const int h = wave >> 1, sub = wave & 1;
    bf16x8 qb[2][4];
#pragma unroll
    for (int nt2 = 0; nt2 < 2; ++nt2)
#pragma unroll
      for (int ks = 0; ks < 4; ++ks)
        qb[nt2][ks] = *(const bf16x8*)(WTq + (h*HD + nt2*16 + l16)*DIM + ks*32 + quad*8);
    const float qbias0 = qkv_b[h*HD + l16];
    const float qbias1 = qkv_b[h*HD + 16 + l16];
    bf16* sQ = sQs + wave*16*SQP;
    bf16* sP = sPs + wave*16*SPP;
    {
      int row = lane >> 2, c0 = 112 + ((lane & 3) << 2);
      uint2 z; z.x = 0; z.y = 0;
      *(uint2*)&sP[row*SPP + c0] = z;
    }
    const float* bias_h = biasf + h*9604;
    const float* mask_w = mask + w*9604;

    f32x4 oacc0 = fzero, oacc1 = fzero;
#pragma unroll 1
    for (int it = 0; it < 4; ++it) {
      const int mt = sub + it*2;
      const bool valid = mt < 7;
      if (valid) {
        f32x4 qa0 = fzero, qa1 = fzero;
#pragma unroll
        for (int ks = 0; ks < 4; ++ks) {
          const bf16x8 a = *(const bf16x8*)&sX[(mt*16 + l16)*SXP + ks*32 + quad*8];
          qa0 = __builtin_amdgcn_mfma_f32_16x16x32_bf16(a, qb[0][ks], qa0, 0, 0, 0);
          qa1 = __builtin_amdgcn_mfma_f32_16x16x32_bf16(a, qb[1][ks], qa1, 0, 0, 0);
        }
#pragma unroll
        for (int r = 0; r < 4; ++r) {
          sQ[(quad*4 + r)*SQP + l16]      = (bf16)((qa0[r] + qbias0) * SCALE_Q);
          sQ[(quad*4 + r)*SQP + 16 + l16] = (bf16)((qa1[r] + qbias1) * SCALE_Q);
        }
        const bf16x8 aq = *(const bf16x8*)&sQ[l16*SQP + quad*8];
        f32x4 s[7];
#pragma unroll
        for (int nt = 0; nt < 7; ++nt) {
          const bf16x8 bk2 = *(const bf16x8*)&sK[(h*NP + nt*16 + l16)*SKP + quad*8];
          s[nt] = __builtin_amdgcn_mfma_f32_16x16x32_bf16(aq, bk2, fzero, 0, 0, 0);
        }
#pragma unroll
        for (int r = 0; r < 4; ++r) {
          const int row = mt*16 + quad*4 + r;
          const bool rowok = row < NTOK;
          float mx = -3.0e38f;
#pragma unroll
          for (int nt = 0; nt < 7; ++nt) {
            const int col = nt*16 + l16;
            float sv;
            if (rowok && col < NTOK)
              sv = s[nt][r] + bias_h[row*NTOK + col] + mask_w[row*NTOK + col];
            else
              sv = -1.0e30f;
            s[nt][r] = sv;
            mx = fmaxf(mx, sv);
          }
#pragma unroll
          for (int off = 1; off < 16; off <<= 1)
            mx = fmaxf(mx, __shfl_xor(mx, off, 64));
          float sum = 0.f;
#pragma unroll
          for (int nt = 0; nt < 7; ++nt) {
            const float p = __expf(s[nt][r] - mx);
            s[nt][r] = p;
            sum += p;
          }
#pragma unroll
          for (int off = 1; off < 16; off <<= 1)
            sum += __shfl_xor(sum, off, 64);
          const float inv = __builtin_amdgcn_rcpf(sum);
#pragma unroll
          for (int nt = 0; nt < 7; ++nt)
            sP[(quad*4 + r)*SPP + nt*16 + l16] = (bf16)(s[nt][r] * inv);
        }
        oacc0 = fzero; oacc1 = fzero;
#pragma unroll
        for (int ks = 0; ks < 4; ++ks) {
          const bf16x8 ap = *(const bf16x8*)&sP[l16*SPP + ks*32 + quad*8];
          const bf16x8 bv0 = *(const bf16x8*)&sVT[(h*HD + l16)*SVP + ks*32 + quad*8];
          const bf16x8 bv1 = *(const bf16x8*)&sVT[(h*HD + 16 + l16)*SVP + ks*32 + quad*8];
          oacc0 = __builtin_amdgcn_mfma_f32_16x16x32_bf16(ap, bv0, oacc0, 0, 0, 0);
          oacc1 = __builtin_amdgcn_mfma_f32_16x16x32_bf16(ap, bv1, oacc1, 0, 0, 0);
        }
      }
      __syncthreads();
      if (valid) {
#pragma unroll
        for (int r = 0; r < 4; ++r) {
          sX[(mt*16 + quad*4 + r)*SXP + h*HD + l16]      = (bf16)(oacc0[r]);
          sX[(mt*16 + quad*4 + r)*SXP + h*HD + 16 + l16] = (bf16)(oacc1[r]);
        }
      }
    }
  }
  __syncthreads();

  {
    const int nt = wave;
    bf16x8 pbf[4];
#pragma unroll
    for (int ks = 0; ks < 4; ++ks)
      pbf[ks] = *(const bf16x8*)(PT + (nt*16 + l16)*DIM + ks*32 + quad*8);
    const float pb = proj_b[nt*16 + l16];
    float* outb = out + (size_t)b * (NTOK*DIM);
#pragma unroll
    for (int mt = 0; mt < 7; ++mt) {
      f32x4 acc = fzero;
#pragma unroll
      for (int ks = 0; ks < 4; ++ks) {
        const bf16x8 a = *(const bf16x8*)&sX[(mt*16 + l16)*SXP + ks*32 + quad*8];
        acc = __builtin_amdgcn_mfma_f32_16x16x32_bf16(a, pbf[ks], acc, 0, 0, 0);
      }
#pragma unroll
      for (int r = 0; r < 4; ++r) {
        const int row = mt*16 + quad*4 + r;
        if (row < NTOK)
          outb[row*DIM + nt*16 + l16] = acc[r] + pb;
      }
    }
  }
}

extern "C" void kernel_launch(void* const* d_in, const int* in_sizes, int n_in,
                              void* d_out, int out_size, void* d_ws, size_t ws_size,
                              hipStream_t stream)
{
  const float* x      = (const float*)d_in[0];
  const float* mask   = (const float*)d_in[1];
  const float* qkv_w  = (const float*)d_in[2];
  const float* qkv_b  = (const float*)d_in[3];
  const float* table  = (const float*)d_in[4];
  const int*   rel    = (const int*)d_in[5];
  const float* proj_w = (const float*)d_in[6];
  const float* proj_b = (const float*)d_in[7];
  float* out = (float*)d_out;
  char* ws = (char*)d_ws;

  if (ws_size >= WS_NEED) {
    bf16*  WTq = (bf16*)(ws + WS_WTQ);
    bf16*  PT  = (bf16*)(ws + WS_PT);
    float* bm2 = (float*)(ws + WS_BM);
    bf16*  Qs  = (bf16*)(ws + WS_QS);
    bf16*  Ks  = (bf16*)(ws + WS_KS);
    bf16*  VTs = (bf16*)(ws + WS_VTS);

    prep2_kernel<<<(384*128 + 128*128 + 255)/256, 256, 0, stream>>>(qkv_w, proj_w, WTq, PT);
    bm_kernel<<<(64*4*98*112 + 255)/256, 256, 0, stream>>>(table, rel, mask, bm2);
    qkv_kernel<<<2048, 512, 0, stream>>>(x, qkv_b, WTq, Qs, Ks, VTs);
    attn_kernel<<<2048, 256, 0, stream>>>(proj_b, Qs, Ks, VTs, PT, bm2, out);
  } else {
    bf16*  WTq   = (bf16*)(ws + WS_WTQ);
    bf16*  PT    = (bf16*)(ws + WS_PT);
    float* biasf = (float*)(ws + WS_BM);
    const int prep_total = 384*128 + 128*128 + 98*98;
    prep_kernel<<<(prep_total + 255)/256, 256, 0, stream>>>(qkv_w, proj_w, table, rel, WTq, PT, biasf);
    win_attn_kernel<<<2048, 512, 0, stream>>>(x, mask, qkv_b, proj_b, WTq, PT, biasf, out);
  }
}